// Round 1
// baseline (5002.537 us; speedup 1.0000x reference)
//
#include <hip/hip_runtime.h>

// Problem dims
#define TT 32
#define BB 8
#define DD 512
#define HH 512
#define RR 32
#define OO 512
#define H2 1024

// d_ws float-index offsets (total ~1.71 MB required)
#define OFF_WX     0        // [TT][BB][H2]      262144
#define OFF_HS     262144   // [TT][BB][HH]      131072
#define OFF_WHPRE  393216   // [2][BB][H2]        16384
#define OFF_STATS  409600   // [2][BB][2]            32
#define OFF_MODPRE 409632   // [2][BB][RR]          512
#define OFF_NH     410144   // [2][BB][HH]         8192
#define OFF_TE     418336   // [2][BB][HH]         8192
#define OFF_BAR    426528   // 16 x unsigned (cnt[8], gen[8])

// ---------------- per-batch grid barrier (32 member blocks) ----------------
__device__ __forceinline__ void batch_bar(unsigned* __restrict__ barctl, int b) {
  __syncthreads();
  __threadfence();  // release: make this block's global writes device-visible
  if (threadIdx.x == 0) {
    unsigned* cnt = barctl + b;
    unsigned* gen = barctl + 8 + b;
    unsigned g0   = __hip_atomic_load(gen, __ATOMIC_ACQUIRE, __HIP_MEMORY_SCOPE_AGENT);
    unsigned prev = __hip_atomic_fetch_add(cnt, 1u, __ATOMIC_ACQ_REL, __HIP_MEMORY_SCOPE_AGENT);
    if (prev == 31u) {               // last arriver of this batch group
      __hip_atomic_store(cnt, 0u, __ATOMIC_RELAXED, __HIP_MEMORY_SCOPE_AGENT);
      __hip_atomic_fetch_add(gen, 1u, __ATOMIC_ACQ_REL, __HIP_MEMORY_SCOPE_AGENT);
    } else {
      while (__hip_atomic_load(gen, __ATOMIC_ACQUIRE, __HIP_MEMORY_SCOPE_AGENT) == g0) {
        __builtin_amdgcn_s_sleep(2);
      }
    }
  }
  __syncthreads();
  __threadfence();  // acquire: invalidate so subsequent loads see fresh data
}

// ---------------- fused state-update + plast + Wh GEMV + LN-stats ----------------
// Thread mapping: il = tid>>5 (row 0..15), m = tid&31; element j = 4*(m+32q)+c.
template<bool UPDATE>
__device__ __forceinline__ void gemv_core(
    int b, int i0, int il, int m, int gi, int tid, int ir, int wp,
    float4 (&dUr)[4], float4 (&tEr)[4],
    const float4 (&Wdvr)[4], const float4 (&upr)[4], const float4 (&lor)[4],
    float s_b, float c1t, float c2t, float sp_alpha,
    const float4* __restrict__ nh4_s, const float4* __restrict__ te4_s,
    const float* __restrict__ nh_s, const float* __restrict__ te_s,
    float* __restrict__ colv_s,
    const float* __restrict__ h2h_w, const float* __restrict__ h2h_b,
    const float* __restrict__ h2mod_b,
    float* __restrict__ WhPre, float* __restrict__ stats, float* __restrict__ modPre)
{
  const float nh_i = nh_s[gi];
  const float te_i = UPDATE ? te_s[gi] : 0.0f;
  float plast = 0.0f, gdv = 0.0f;
#pragma unroll
  for (int q = 0; q < 4; ++q) {
    const int J = m + 32 * q;
    const float4 nh4 = nh4_s[J];
    if (UPDATE) {
      const float4 te4 = te4_s[J];
#define SGRU_UPD(C) { \
      float o   = nh_i * te4.C - nh4.C * te_i;              /* outer - outer^T  */ \
      float tEn = tEr[q].C + s_b * (o - tEr[q].C);          /* (1-s)tE + s*o    */ \
      tEr[q].C  = tEn;                                                              \
      float d   = c1t * dUr[q].C + c2t * tEn;               /* (1-tau)dU+tau*m*tE */ \
      d = fminf(d, upr[q].C); d = fmaxf(d, lor[q].C);       /* clip             */ \
      dUr[q].C  = d;                                                                \
      plast = fmaf(d, nh4.C, plast); }
      SGRU_UPD(x) SGRU_UPD(y) SGRU_UPD(z) SGRU_UPD(w)
#undef SGRU_UPD
    } else {
      plast += dUr[q].x*nh4.x + dUr[q].y*nh4.y + dUr[q].z*nh4.z + dUr[q].w*nh4.w;
    }
    gdv += Wdvr[q].x*nh4.x + Wdvr[q].y*nh4.y + Wdvr[q].z*nh4.z + Wdvr[q].w*nh4.w;
  }
#pragma unroll
  for (int off = 16; off >= 1; off >>= 1) {
    plast += __shfl_xor(plast, off);
    gdv   += __shfl_xor(gdv, off);
  }
  if (m == 0) {  // high column H+gi: Wdv·nh + bias + sp_alpha*plast
    const float val = gdv + h2h_b[HH + gi] + sp_alpha * plast;
    WhPre[wp*(BB*H2) + b*H2 + HH + gi] = val;
    colv_s[16 + il] = val;
  }
  // low column i0+il: stream weight row from L2
  float accl = 0.0f;
  const float* wrow = h2h_w + (size_t)(i0 + il) * HH;
#pragma unroll
  for (int q = 0; q < 4; ++q) {
    const int J = m + 32 * q;
    const float4 w4  = *reinterpret_cast<const float4*>(wrow + 4*J);
    const float4 nh4 = nh4_s[J];
    accl += w4.x*nh4.x + w4.y*nh4.y + w4.z*nh4.z + w4.w*nh4.w;
  }
#pragma unroll
  for (int off = 16; off >= 1; off >>= 1) accl += __shfl_xor(accl, off);
  if (m == 0) {
    const float val = accl + h2h_b[i0 + il];
    WhPre[wp*(BB*H2) + b*H2 + i0 + il] = val;
    colv_s[il] = val;
  }
  __syncthreads();
  if (tid == 0) {  // one atomic pair per block for LN stats
    float s1 = 0.0f, s2 = 0.0f;
#pragma unroll
    for (int c = 0; c < 32; ++c) { const float v = colv_s[c]; s1 += v; s2 += v*v; }
    atomicAdd(&stats[wp*16 + b*2 + 0], s1);
    atomicAdd(&stats[wp*16 + b*2 + 1], s2);
  }
  if (ir == 0 && tid < RR) modPre[wp*(BB*RR) + b*RR + tid] = h2mod_b[tid];  // init next modPre = bias
}

// ---------------- persistent recurrent kernel ----------------
__global__ __launch_bounds__(512, 1) void sgru_persistent(
    const float* __restrict__ h0,     const float* __restrict__ v0,
    const float* __restrict__ dU0,    const float* __restrict__ tE0,
    const float* __restrict__ te0,
    const float* __restrict__ h2h_w,  const float* __restrict__ h2h_b,
    const float* __restrict__ lnh_g,  const float* __restrict__ lnh_b,
    const float* __restrict__ h2mod_w,const float* __restrict__ h2mod_b,
    const float* __restrict__ mod2h_w,const float* __restrict__ mod2h_b,
    const float* __restrict__ alpha_p,const float* __restrict__ tau_p,
    float* __restrict__ ws, unsigned* __restrict__ barctl)
{
  const int tid = threadIdx.x;
  const int b   = blockIdx.x & 7;    // batch: consecutive blockIdx -> XCD round-robin keeps batch on one XCD
  const int ir  = blockIdx.x >> 3;   // row-group 0..31
  const int i0  = ir << 4;           // first owned row
  const int il  = tid >> 5;          // row within group 0..15
  const int m   = tid & 31;          // lane within row-group
  const int gi  = i0 + il;           // global row index

  float* Wx     = ws + OFF_WX;
  float* hsbuf  = ws + OFF_HS;
  float* WhPre  = ws + OFF_WHPRE;
  float* stats  = ws + OFF_STATS;
  float* modPre = ws + OFF_MODPRE;
  float* nhBuf  = ws + OFF_NH;
  float* teBuf  = ws + OFF_TE;

  __shared__ float4 nh4_s[128];
  __shared__ float4 te4_s[128];
  __shared__ float  mp_s[RR];
  __shared__ float  rsm_s[3];
  __shared__ float  colv_s[32];
  __shared__ float  nh16_s[16];
  float* nh_s = reinterpret_cast<float*>(nh4_s);
  float* te_s = reinterpret_cast<float*>(te4_s);

  const float a_sp  = log1pf(expf(alpha_p[0]));          // softplus(alpha)
  const float inv_a = 1.0f / (a_sp + 1e-8f);
  const float tau   = 1.0f / (1.0f + expf(-tau_p[0]));   // sigmoid(tau_U)
  const float c1t   = 1.0f - tau;

  // register-resident state: dU, tE, w_dv row, clip bounds  (16 elems each)
  float4 dUr[4], tEr[4], Wdvr[4], upr[4], lor[4];
  {
    const size_t rowoff = ((size_t)b * HH + gi) * HH;
    const size_t woff   = (size_t)(HH + gi) * HH;
#pragma unroll
    for (int q = 0; q < 4; ++q) {
      const int J = m + 32 * q;
      dUr[q] = *reinterpret_cast<const float4*>(dU0 + rowoff + 4*J);
      tEr[q] = *reinterpret_cast<const float4*>(tE0 + rowoff + 4*J);
      const float4 w = *reinterpret_cast<const float4*>(h2h_w + woff + 4*J);
      Wdvr[q] = w;
      float4 u, l;
      u.x =  fmaxf(1.0f - w.x, 0.0f) * inv_a;  l.x = -fmaxf(1.0f + w.x, 0.0f) * inv_a;
      u.y =  fmaxf(1.0f - w.y, 0.0f) * inv_a;  l.y = -fmaxf(1.0f + w.y, 0.0f) * inv_a;
      u.z =  fmaxf(1.0f - w.z, 0.0f) * inv_a;  l.z = -fmaxf(1.0f + w.z, 0.0f) * inv_a;
      u.w =  fmaxf(1.0f - w.w, 0.0f) * inv_a;  l.w = -fmaxf(1.0f + w.w, 0.0f) * inv_a;
      upr[q] = u; lor[q] = l;
    }
  }

  float vreg = (tid < 16) ? v0[b*HH + i0 + tid] : 0.0f;  // v state, owned by threads 0..15

  // nh_s <- h0 for the prologue GEMV
  for (int j = tid; j < HH; j += 512) nh_s[j] = h0[b*HH + j];

  if (ir == 0) {
    for (int j = tid; j < HH; j += 512) {
      teBuf[0*(BB*HH) + b*HH + j] = te0[b*HH + j];   // te entering step 0
      nhBuf[1*(BB*HH) + b*HH + j] = h0[b*HH + j];    // h_prev for step 0
    }
    if (tid < 2) stats[0*16 + b*2 + tid] = 0.0f;
  }

  batch_bar(barctl, b);

  // prologue = "phase 2 of step -1": Wh(0), plast(0), stats(0), modPre(0)=bias
  gemv_core<false>(b, i0, il, m, gi, tid, ir, /*wp=*/0,
                   dUr, tEr, Wdvr, upr, lor,
                   0.0f, c1t, 0.0f, a_sp,
                   nh4_s, te4_s, nh_s, te_s, colv_s,
                   h2h_w, h2h_b, h2mod_b, WhPre, stats, modPre);

  batch_bar(barctl, b);

  for (int t = 0; t < TT; ++t) {
    const int p = t & 1;
    // ---------------- phase 1: LN -> z,dv -> v,nh ; modulator partials ----------------
    if (tid < 16) {
      const int i = i0 + tid;
      const float s1 = stats[p*16 + b*2 + 0];
      const float s2 = stats[p*16 + b*2 + 1];
      const float mu   = s1 * (1.0f / H2);
      const float var  = s2 * (1.0f / H2) - mu * mu;
      const float rstd = rsqrtf(var + 1e-5f);
      const float* wh  = WhPre + p*(BB*H2) + b*H2;
      const float* wxr = Wx + (size_t)(t*BB + b) * H2;
      const float yz = (wh[i]      - mu)*rstd*lnh_g[i]      + lnh_b[i]      + wxr[i];
      const float yd = (wh[HH + i] - mu)*rstd*lnh_g[HH + i] + lnh_b[HH + i] + wxr[HH + i];
      const float z  = 1.0f / (1.0f + expf(-yz));
      const float vn = vreg + z * (yd - vreg);          // (1-z)v + z*dv
      vreg = vn;
      const float nh = fmaxf(vn, 0.0f);
      nhBuf[p*(BB*HH) + b*HH + i]       = nh;
      hsbuf[(size_t)(t*BB + b)*HH + i]  = nh;
      nh16_s[tid] = nh;
    }
    if (ir == 0 && (tid == 32 || tid == 33)) stats[(1-p)*16 + b*2 + (tid - 32)] = 0.0f;
    __syncthreads();
    if (tid < RR) {
      float part = 0.0f;
#pragma unroll
      for (int ii = 0; ii < 16; ++ii)
        part += h2mod_w[(size_t)tid*HH + i0 + ii] * nh16_s[ii];
      atomicAdd(&modPre[p*(BB*RR) + b*RR + tid], part);
    }
    if (t == TT - 1) return;   // uniform exit: hs complete, decode kernel follows
    batch_bar(barctl, b);

    // ---------------- phase 2: r/s/m, te_n, state update + next GEMV ----------------
    if (tid < RR) mp_s[tid] = fmaxf(modPre[p*(BB*RR) + b*RR + tid], 0.0f);
    __syncthreads();
    if (tid == 0) {
      float c0 = mod2h_b[0], c1 = mod2h_b[1], c2 = mod2h_b[2];
      for (int r = 0; r < RR; ++r) {
        const float vv = mp_s[r];
        c0 += mod2h_w[r]        * vv;
        c1 += mod2h_w[RR + r]   * vv;
        c2 += mod2h_w[2*RR + r] * vv;
      }
      rsm_s[0] = 1.0f / (1.0f + expf(-c0));   // r
      rsm_s[1] = 1.0f / (1.0f + expf(-c1));   // s
      rsm_s[2] = c2;                          // m
    }
    __syncthreads();
    const float r_b = rsm_s[0];
    const float s_b = rsm_s[1];
    const float c2t = tau * rsm_s[2];
    {
      const int j = tid;
      const float teo = teBuf[p*(BB*HH) + b*HH + j];
      const float hp  = nhBuf[(1-p)*(BB*HH) + b*HH + j];
      const float ten = teo + r_b * (hp - teo);         // (1-r)te + r*h
      te_s[j] = ten;
      nh_s[j] = nhBuf[p*(BB*HH) + b*HH + j];
      if (ir == 0) teBuf[(1-p)*(BB*HH) + b*HH + j] = ten;
    }
    __syncthreads();
    gemv_core<true>(b, i0, il, m, gi, tid, ir, /*wp=*/1 - p,
                    dUr, tEr, Wdvr, upr, lor,
                    s_b, c1t, c2t, a_sp,
                    nh4_s, te4_s, nh_s, te_s, colv_s,
                    h2h_w, h2h_b, h2mod_b, WhPre, stats, modPre);
    batch_bar(barctl, b);
  }
}

// ---------------- Wx = LN(x @ x2h_w^T + b) precompute (also zeroes barrier ctl) ----------------
__global__ __launch_bounds__(256) void wx_ln_kernel(
    const float* __restrict__ x, const float* __restrict__ w,
    const float* __restrict__ bias, const float* __restrict__ g,
    const float* __restrict__ bvec, float* __restrict__ Wx,
    unsigned* __restrict__ barctl)
{
  if (blockIdx.x == 0 && threadIdx.x < 16) barctl[threadIdx.x] = 0u;
  const int tid  = threadIdx.x;
  const int row0 = blockIdx.x * 4;   // rows = t*8+b, 4 per block, 64 blocks
  __shared__ float xs[4][DD];
  __shared__ float outs[4][H2];
  __shared__ float wred[2][4];
  __shared__ float stat_s[2];
  for (int idx = tid; idx < 4*DD; idx += 256)
    xs[idx >> 9][idx & (DD-1)] = x[(size_t)row0*DD + idx];
  __syncthreads();
  float acc[4][4];
#pragma unroll
  for (int r = 0; r < 4; ++r)
#pragma unroll
    for (int c = 0; c < 4; ++c) acc[r][c] = 0.0f;
  for (int j = 0; j < DD; ++j) {
    const float x0 = xs[0][j], x1 = xs[1][j], x2 = xs[2][j], x3 = xs[3][j];
#pragma unroll
    for (int c = 0; c < 4; ++c) {
      const float wv = w[(size_t)(tid + 256*c)*DD + j];
      acc[0][c] += wv*x0; acc[1][c] += wv*x1; acc[2][c] += wv*x2; acc[3][c] += wv*x3;
    }
  }
#pragma unroll
  for (int r = 0; r < 4; ++r)
#pragma unroll
    for (int c = 0; c < 4; ++c)
      outs[r][tid + 256*c] = acc[r][c] + bias[tid + 256*c];
  __syncthreads();
  for (int r = 0; r < 4; ++r) {
    float s1 = 0.0f, s2 = 0.0f;
#pragma unroll
    for (int c = 0; c < 4; ++c) { const float v = outs[r][tid + 256*c]; s1 += v; s2 += v*v; }
#pragma unroll
    for (int off = 32; off >= 1; off >>= 1) { s1 += __shfl_down(s1, off); s2 += __shfl_down(s2, off); }
    if ((tid & 63) == 0) { wred[0][tid >> 6] = s1; wred[1][tid >> 6] = s2; }
    __syncthreads();
    if (tid == 0) {
      const float t1 = wred[0][0] + wred[0][1] + wred[0][2] + wred[0][3];
      const float t2 = wred[1][0] + wred[1][1] + wred[1][2] + wred[1][3];
      const float mu = t1 * (1.0f / H2);
      const float var = t2 * (1.0f / H2) - mu * mu;
      stat_s[0] = mu;
      stat_s[1] = rsqrtf(var + 1e-5f);
    }
    __syncthreads();
    const float mu = stat_s[0], rstd = stat_s[1];
#pragma unroll
    for (int c = 0; c < 4; ++c) {
      const int k = tid + 256*c;
      Wx[((size_t)row0 + r)*H2 + k] = g[k]*(outs[r][k] - mu)*rstd + bvec[k];
    }
    __syncthreads();
  }
}

// ---------------- out = hs @ dec_w^T + dec_b ----------------
__global__ __launch_bounds__(256) void decode_kernel(
    const float* __restrict__ hsbuf, const float* __restrict__ w,
    const float* __restrict__ bias, float* __restrict__ out)
{
  const int tid  = threadIdx.x;
  const int row0 = blockIdx.x * 4;
  __shared__ float hsr[4][HH];
  for (int idx = tid; idx < 4*HH; idx += 256)
    hsr[idx >> 9][idx & (HH-1)] = hsbuf[(size_t)row0*HH + idx];
  __syncthreads();
  float a0[4] = {0,0,0,0}, a1[4] = {0,0,0,0};
  const float* w0 = w + (size_t)tid*HH;
  const float* w1 = w + (size_t)(tid + 256)*HH;
  for (int j = 0; j < HH; ++j) {
    const float wv0 = w0[j], wv1 = w1[j];
    const float h0v = hsr[0][j], h1v = hsr[1][j], h2v = hsr[2][j], h3v = hsr[3][j];
    a0[0] += wv0*h0v; a0[1] += wv0*h1v; a0[2] += wv0*h2v; a0[3] += wv0*h3v;
    a1[0] += wv1*h0v; a1[1] += wv1*h1v; a1[2] += wv1*h2v; a1[3] += wv1*h3v;
  }
  const float b0 = bias[tid], b1 = bias[tid + 256];
#pragma unroll
  for (int r = 0; r < 4; ++r) {
    out[((size_t)row0 + r)*OO + tid]       = a0[r] + b0;
    out[((size_t)row0 + r)*OO + tid + 256] = a1[r] + b1;
  }
}

extern "C" void kernel_launch(void* const* d_in, const int* in_sizes, int n_in,
                              void* d_out, int out_size, void* d_ws, size_t ws_size,
                              hipStream_t stream) {
  (void)in_sizes; (void)n_in; (void)out_size; (void)ws_size;
  const float* x        = (const float*)d_in[0];
  const float* h0       = (const float*)d_in[1];
  const float* v0       = (const float*)d_in[2];
  const float* dU0      = (const float*)d_in[3];
  const float* te0      = (const float*)d_in[4];   // trace_e0
  const float* tE0      = (const float*)d_in[5];   // trace_E0
  const float* x2h_w    = (const float*)d_in[6];
  const float* x2h_b    = (const float*)d_in[7];
  const float* h2h_w    = (const float*)d_in[8];
  const float* h2h_b    = (const float*)d_in[9];
  const float* lnx_g    = (const float*)d_in[10];
  const float* lnx_b    = (const float*)d_in[11];
  const float* lnh_g    = (const float*)d_in[12];
  const float* lnh_b    = (const float*)d_in[13];
  const float* h2mod_w  = (const float*)d_in[14];
  const float* h2mod_b  = (const float*)d_in[15];
  const float* mod2h_w  = (const float*)d_in[16];
  const float* mod2h_b  = (const float*)d_in[17];
  const float* alpha    = (const float*)d_in[18];
  const float* tau_U    = (const float*)d_in[19];
  const float* dec_w    = (const float*)d_in[20];
  const float* dec_b    = (const float*)d_in[21];

  float* ws = (float*)d_ws;
  unsigned* barctl = (unsigned*)(ws + OFF_BAR);

  // 1) precompute Wx (also zeroes barrier control words each call)
  wx_ln_kernel<<<64, 256, 0, stream>>>(x, x2h_w, x2h_b, lnx_g, lnx_b, ws + OFF_WX, barctl);

  // 2) persistent recurrent kernel: 256 blocks (= #CUs, 1/CU), 512 threads
  sgru_persistent<<<256, 512, 0, stream>>>(h0, v0, dU0, tE0, te0,
                                           h2h_w, h2h_b, lnh_g, lnh_b,
                                           h2mod_w, h2mod_b, mod2h_w, mod2h_b,
                                           alpha, tau_U, ws, barctl);

  // 3) decode
  decode_kernel<<<64, 256, 0, stream>>>(ws + OFF_HS, dec_w, dec_b, (float*)d_out);
}

// Round 2
// 386.955 us; speedup vs baseline: 12.9279x; 12.9279x over previous
//
#include <hip/hip_runtime.h>

// Problem dims
#define TT 32
#define BB 8
#define DD 512
#define HH 512
#define RR 32
#define OO 512
#define H2 1024

typedef unsigned long long ull;

// d_ws float-index offsets (~1.52 MB used)
#define OFF_WX     0        // [TT][BB][H2]      262144
#define OFF_HS     262144   // [TT][BB][HH]      131072
#define OFF_NH     393216   // [BB][HH]            4096   (coherent nh exchange)
#define OFF_STATS  397312   // [2][BB][2]            32   (coherent LN stats)
#define OFF_MODPRE 397344   // [2][BB][RR]          512   (coherent mod partials)
#define OFF_BAR    397856   // 264 x u32: flags[8][32], gens[8]

#define AGENT __HIP_MEMORY_SCOPE_AGENT
#define RLX   __ATOMIC_RELAXED

__device__ __forceinline__ void st_coh(float* p, float v) {
  __hip_atomic_store(p, v, RLX, AGENT);
}
__device__ __forceinline__ float ld_coh(const float* p) {
  return __hip_atomic_load(const_cast<float*>(p), RLX, AGENT);
}
__device__ __forceinline__ void add_coh(float* p, float v) {
  __hip_atomic_fetch_add(p, v, RLX, AGENT);
}

// ---------------- fence-free per-batch barrier (32 member blocks) ----------------
// flags[b*32+ir] and gens[b] are monotonically increasing sequence tags.
// Protocol: drain own stores (vmcnt) -> post flag=seq -> master polls all 32
// flags >= seq -> master posts gen=seq -> others poll gen >= seq.
// All ops relaxed agent-scope (sc-coherent): NO buffer_wbl2 / buffer_inv ever.
__device__ __forceinline__ void batch_bar(unsigned* flags, unsigned* gens,
                                          int b, int ir, unsigned seq) {
  __syncthreads();
  asm volatile("s_waitcnt vmcnt(0)" ::: "memory");
  const int tid = threadIdx.x;
  if (tid == 0)
    __hip_atomic_store(&flags[b*32 + ir], seq, RLX, AGENT);
  asm volatile("" ::: "memory");  // compiler barrier: flag store precedes polls
  if (ir == 0) {
    if (tid < 64) {
      ull* f64 = (ull*)(flags + b*32);
      for (;;) {
        bool ok = true;
        if (tid < 16) {
          ull v = __hip_atomic_load(&f64[tid], RLX, AGENT);
          ok = ((unsigned)v >= seq) && ((unsigned)(v >> 32) >= seq);
        }
        if (__all(ok)) break;
        __builtin_amdgcn_s_sleep(1);
      }
      if (tid == 0)
        __hip_atomic_store(&gens[b], seq, RLX, AGENT);
    }
  } else {
    if (tid == 0) {
      while (__hip_atomic_load(&gens[b], RLX, AGENT) < seq)
        __builtin_amdgcn_s_sleep(1);
    }
  }
  __syncthreads();
}

// ---------------- fused state-update + plast + Wh GEMV + LN-stats ----------------
// il = tid>>5 (row 0..15), m = tid&31; element j = 4*(m+32q)+c.
template<bool UPDATE>
__device__ __forceinline__ void gemv_core(
    int b, int i0, int il, int m, int gi, int tid, int ir, int wp,
    float4 (&dUr)[4], float4 (&tEr)[4],
    const float4 (&Wdvr)[4], const float4 (&upr)[4], const float4 (&lor)[4],
    float s_b, float c1t, float c2t, float sp_alpha,
    const float4* nh4_s, const float4* te4_s,
    const float* nh_s, const float* te_s,
    float* colv_s,
    const float* __restrict__ h2h_w, const float* __restrict__ h2h_b,
    const float* __restrict__ h2mod_b,
    float* stats, float* modPre)
{
  const float nh_i = nh_s[gi];
  const float te_i = UPDATE ? te_s[gi] : 0.0f;
  float plast = 0.0f, gdv = 0.0f;
#pragma unroll
  for (int q = 0; q < 4; ++q) {
    const int J = m + 32 * q;
    const float4 nh4 = nh4_s[J];
    if (UPDATE) {
      const float4 te4 = te4_s[J];
#define SGRU_UPD(C) { \
      float o   = nh_i * te4.C - nh4.C * te_i;              /* outer - outer^T    */ \
      float tEn = tEr[q].C + s_b * (o - tEr[q].C);          /* (1-s)tE + s*o      */ \
      tEr[q].C  = tEn;                                                               \
      float d   = c1t * dUr[q].C + c2t * tEn;               /* (1-tau)dU+tau*m*tE */ \
      d = fminf(d, upr[q].C); d = fmaxf(d, lor[q].C);       /* clip               */ \
      dUr[q].C  = d;                                                                 \
      plast = fmaf(d, nh4.C, plast); }
      SGRU_UPD(x) SGRU_UPD(y) SGRU_UPD(z) SGRU_UPD(w)
#undef SGRU_UPD
    } else {
      plast += dUr[q].x*nh4.x + dUr[q].y*nh4.y + dUr[q].z*nh4.z + dUr[q].w*nh4.w;
    }
    gdv += Wdvr[q].x*nh4.x + Wdvr[q].y*nh4.y + Wdvr[q].z*nh4.z + Wdvr[q].w*nh4.w;
  }
  // low column i0+il: stream weight row (stays hot in L1/L2 — no invalidations)
  float accl = 0.0f;
  const float* wrow = h2h_w + (size_t)(i0 + il) * HH;
#pragma unroll
  for (int q = 0; q < 4; ++q) {
    const int J = m + 32 * q;
    const float4 w4  = *reinterpret_cast<const float4*>(wrow + 4*J);
    const float4 nh4 = nh4_s[J];
    accl += w4.x*nh4.x + w4.y*nh4.y + w4.z*nh4.z + w4.w*nh4.w;
  }
#pragma unroll
  for (int off = 16; off >= 1; off >>= 1) {
    plast += __shfl_xor(plast, off);
    gdv   += __shfl_xor(gdv, off);
    accl  += __shfl_xor(accl, off);
  }
  if (m == 0) {
    colv_s[16 + il] = gdv + h2h_b[HH + gi] + sp_alpha * plast;  // high col H+gi
    colv_s[il]      = accl + h2h_b[i0 + il];                    // low col i0+il
  }
  __syncthreads();
  if (tid < 64) {   // wave 0: LN-stats partial over this block's 32 columns
    const float v = (tid < 32) ? colv_s[tid] : 0.0f;
    float s1 = v, s2 = v * v;
#pragma unroll
    for (int off = 16; off >= 1; off >>= 1) {
      s1 += __shfl_xor(s1, off);
      s2 += __shfl_xor(s2, off);
    }
    if (tid == 0) {
      add_coh(&stats[wp*16 + b*2 + 0], s1);
      add_coh(&stats[wp*16 + b*2 + 1], s2);
    }
  }
  if (ir == 0 && tid < RR)   // init next accumulation buffer = bias
    st_coh(&modPre[wp*(BB*RR) + b*RR + tid], h2mod_b[tid]);
}

// ---------------- persistent recurrent kernel ----------------
__global__ __launch_bounds__(512, 1) void sgru_persistent(
    const float* __restrict__ h0,     const float* __restrict__ v0,
    const float* __restrict__ dU0,    const float* __restrict__ tE0,
    const float* __restrict__ te0,
    const float* __restrict__ h2h_w,  const float* __restrict__ h2h_b,
    const float* __restrict__ lnh_g,  const float* __restrict__ lnh_b,
    const float* __restrict__ h2mod_w,const float* __restrict__ h2mod_b,
    const float* __restrict__ mod2h_w,const float* __restrict__ mod2h_b,
    const float* __restrict__ alpha_p,const float* __restrict__ tau_p,
    float* __restrict__ ws)
{
  const int tid = threadIdx.x;
  const int b   = blockIdx.x & 7;
  const int ir  = blockIdx.x >> 3;
  const int i0  = ir << 4;
  const int il  = tid >> 5;
  const int m   = tid & 31;
  const int gi  = i0 + il;

  const float* Wx = ws + OFF_WX;
  float* hsbuf  = ws + OFF_HS;
  float* nhG    = ws + OFF_NH;
  float* stats  = ws + OFF_STATS;
  float* modPre = ws + OFF_MODPRE;
  unsigned* flags = (unsigned*)(ws + OFF_BAR);
  unsigned* gens  = flags + 256;
  ull* nhG64 = (ull*)nhG;

  __shared__ float4 buf0_s[128];   // nh double buffer (cur/prev by parity)
  __shared__ float4 buf1_s[128];
  __shared__ float4 te4_s[128];    // block-local te (redundant per block)
  __shared__ float  colv_s[32];
  __shared__ float  nh16_s[16];
  __shared__ float  rsm_s[4];
  float* buf0 = reinterpret_cast<float*>(buf0_s);
  float* buf1 = reinterpret_cast<float*>(buf1_s);
  float* te_s = reinterpret_cast<float*>(te4_s);

  const float a_sp  = log1pf(__expf(alpha_p[0]));
  const float inv_a = 1.0f / (a_sp + 1e-8f);
  const float tau   = 1.0f / (1.0f + __expf(-tau_p[0]));
  const float c1t   = 1.0f - tau;

  // register-resident state: dU, tE, w_dv row, clip bounds (16 elems each)
  float4 dUr[4], tEr[4], Wdvr[4], upr[4], lor[4];
  {
    const size_t rowoff = ((size_t)b * HH + gi) * HH;
    const size_t woff   = (size_t)(HH + gi) * HH;
#pragma unroll
    for (int q = 0; q < 4; ++q) {
      const int J = m + 32 * q;
      dUr[q] = *reinterpret_cast<const float4*>(dU0 + rowoff + 4*J);
      tEr[q] = *reinterpret_cast<const float4*>(tE0 + rowoff + 4*J);
      const float4 w = *reinterpret_cast<const float4*>(h2h_w + woff + 4*J);
      Wdvr[q] = w;
      float4 u, l;
      u.x =  fmaxf(1.0f - w.x, 0.0f) * inv_a;  l.x = -fmaxf(1.0f + w.x, 0.0f) * inv_a;
      u.y =  fmaxf(1.0f - w.y, 0.0f) * inv_a;  l.y = -fmaxf(1.0f + w.y, 0.0f) * inv_a;
      u.z =  fmaxf(1.0f - w.z, 0.0f) * inv_a;  l.z = -fmaxf(1.0f + w.z, 0.0f) * inv_a;
      u.w =  fmaxf(1.0f - w.w, 0.0f) * inv_a;  l.w = -fmaxf(1.0f + w.w, 0.0f) * inv_a;
      upr[q] = u; lor[q] = l;
    }
  }

  float vreg = (tid < 16) ? v0[b*HH + i0 + tid] : 0.0f;

  // prologue: h0 -> buf1 (prev for t=0), te0 -> te_s  (block-local loads)
  buf1[tid] = h0[b*HH + tid];
  te_s[tid] = te0[b*HH + tid];
  __syncthreads();

  unsigned seq = 0;

  // prologue = phase 2 of "step -1": colv(0), stats[0] adds, modPre[0]=bias
  gemv_core<false>(b, i0, il, m, gi, tid, ir, /*wp=*/0,
                   dUr, tEr, Wdvr, upr, lor,
                   0.0f, c1t, 0.0f, a_sp,
                   buf1_s, te4_s, buf1, te_s, colv_s,
                   h2h_w, h2h_b, h2mod_b, stats, modPre);
  ++seq; batch_bar(flags, gens, b, ir, seq);

  for (int t = 0; t < TT; ++t) {
    const int p = t & 1;
    float* cur  = p ? buf1 : buf0;
    float* prev = p ? buf0 : buf1;
    const float4* cur4 = p ? buf1_s : buf0_s;

    // ---------------- phase 1: LN -> z,dv -> v,nh ; modulator partials ----------------
    if (tid < 16) {
      const int i = i0 + tid;
      const float s1 = ld_coh(&stats[p*16 + b*2 + 0]);
      const float s2 = ld_coh(&stats[p*16 + b*2 + 1]);
      const float mu   = s1 * (1.0f / H2);
      const float var  = s2 * (1.0f / H2) - mu * mu;
      const float rstd = rsqrtf(var + 1e-5f);
      const float* wxr = Wx + (size_t)(t*BB + b) * H2;
      const float yz = (colv_s[tid]      - mu)*rstd*lnh_g[i]      + lnh_b[i]      + wxr[i];
      const float yd = (colv_s[16 + tid] - mu)*rstd*lnh_g[HH + i] + lnh_b[HH + i] + wxr[HH + i];
      const float z  = 1.0f / (1.0f + __expf(-yz));
      const float vn = vreg + z * (yd - vreg);
      vreg = vn;
      const float nh = fmaxf(vn, 0.0f);
      st_coh(&nhG[b*HH + i], nh);
      hsbuf[(size_t)(t*BB + b)*HH + i] = nh;
      nh16_s[tid] = nh;
    }
    if (ir == 0 && (tid == 32 || tid == 33))
      st_coh(&stats[(1-p)*16 + b*2 + (tid - 32)], 0.0f);
    __syncthreads();
    if (tid < RR) {
      float part = 0.0f;
#pragma unroll
      for (int ii = 0; ii < 16; ++ii)
        part += h2mod_w[(size_t)tid*HH + i0 + ii] * nh16_s[ii];
      add_coh(&modPre[p*(BB*RR) + b*RR + tid], part);
    }
    if (t == TT - 1) return;
    ++seq; batch_bar(flags, gens, b, ir, seq);

    // ---------------- phase 2: gather nh; r/s/m; te; state update + GEMV ----------------
    if (tid < 256)   // coherent gather of full nh vector into LDS
      reinterpret_cast<ull*>(cur)[tid] =
        __hip_atomic_load(&nhG64[b*256 + tid], RLX, AGENT);
    if (tid < 64) {  // wave 0: r/s/m via shuffle reduction
      float mp = 0.0f, w0 = 0.0f, w1 = 0.0f, w2 = 0.0f;
      if (tid < RR) {
        mp = fmaxf(ld_coh(&modPre[p*(BB*RR) + b*RR + tid]), 0.0f);
        w0 = mod2h_w[tid]; w1 = mod2h_w[RR + tid]; w2 = mod2h_w[2*RR + tid];
      }
      float a0 = w0*mp, a1 = w1*mp, a2 = w2*mp;
#pragma unroll
      for (int off = 16; off >= 1; off >>= 1) {
        a0 += __shfl_xor(a0, off);
        a1 += __shfl_xor(a1, off);
        a2 += __shfl_xor(a2, off);
      }
      if (tid == 0) {
        rsm_s[0] = 1.0f / (1.0f + __expf(-(a0 + mod2h_b[0])));
        rsm_s[1] = 1.0f / (1.0f + __expf(-(a1 + mod2h_b[1])));
        rsm_s[2] = a2 + mod2h_b[2];
      }
    }
    __syncthreads();
    const float r_b = rsm_s[0];
    const float s_b = rsm_s[1];
    const float c2t = tau * rsm_s[2];
    {
      const float teo = te_s[tid];
      te_s[tid] = teo + r_b * (prev[tid] - teo);   // (1-r)te + r*h_prev
    }
    __syncthreads();
    gemv_core<true>(b, i0, il, m, gi, tid, ir, /*wp=*/1 - p,
                    dUr, tEr, Wdvr, upr, lor,
                    s_b, c1t, c2t, a_sp,
                    cur4, te4_s, cur, te_s, colv_s,
                    h2h_w, h2h_b, h2mod_b, stats, modPre);
    ++seq; batch_bar(flags, gens, b, ir, seq);
  }
}

// ---------------- Wx = LN(x @ x2h_w^T + b) precompute (also inits sync words) ----------------
__global__ __launch_bounds__(256) void wx_ln_kernel(
    const float* __restrict__ x, const float* __restrict__ w,
    const float* __restrict__ bias, const float* __restrict__ g,
    const float* __restrict__ bvec, float* __restrict__ Wx,
    unsigned* __restrict__ barctl, float* __restrict__ stats)
{
  if (blockIdx.x == 0) {
    if (threadIdx.x < 264) barctl[threadIdx.x] = 0u;   // flags[256] + gens[8]
    if (threadIdx.x < 32)  stats[threadIdx.x] = 0.0f;  // both LN-stat buffers
  }
  const int tid  = threadIdx.x;
  const int row0 = blockIdx.x * 4;
  __shared__ float xs[4][DD];
  __shared__ float outs[4][H2];
  __shared__ float wred[2][4];
  __shared__ float stat_s[2];
  for (int idx = tid; idx < 4*DD; idx += 256)
    xs[idx >> 9][idx & (DD-1)] = x[(size_t)row0*DD + idx];
  __syncthreads();
  float acc[4][4];
#pragma unroll
  for (int r = 0; r < 4; ++r)
#pragma unroll
    for (int c = 0; c < 4; ++c) acc[r][c] = 0.0f;
  for (int j = 0; j < DD; ++j) {
    const float x0 = xs[0][j], x1 = xs[1][j], x2 = xs[2][j], x3 = xs[3][j];
#pragma unroll
    for (int c = 0; c < 4; ++c) {
      const float wv = w[(size_t)(tid + 256*c)*DD + j];
      acc[0][c] += wv*x0; acc[1][c] += wv*x1; acc[2][c] += wv*x2; acc[3][c] += wv*x3;
    }
  }
#pragma unroll
  for (int r = 0; r < 4; ++r)
#pragma unroll
    for (int c = 0; c < 4; ++c)
      outs[r][tid + 256*c] = acc[r][c] + bias[tid + 256*c];
  __syncthreads();
  for (int r = 0; r < 4; ++r) {
    float s1 = 0.0f, s2 = 0.0f;
#pragma unroll
    for (int c = 0; c < 4; ++c) { const float v = outs[r][tid + 256*c]; s1 += v; s2 += v*v; }
#pragma unroll
    for (int off = 32; off >= 1; off >>= 1) { s1 += __shfl_down(s1, off); s2 += __shfl_down(s2, off); }
    if ((tid & 63) == 0) { wred[0][tid >> 6] = s1; wred[1][tid >> 6] = s2; }
    __syncthreads();
    if (tid == 0) {
      const float t1 = wred[0][0] + wred[0][1] + wred[0][2] + wred[0][3];
      const float t2 = wred[1][0] + wred[1][1] + wred[1][2] + wred[1][3];
      const float mu = t1 * (1.0f / H2);
      const float var = t2 * (1.0f / H2) - mu * mu;
      stat_s[0] = mu;
      stat_s[1] = rsqrtf(var + 1e-5f);
    }
    __syncthreads();
    const float mu = stat_s[0], rstd = stat_s[1];
#pragma unroll
    for (int c = 0; c < 4; ++c) {
      const int k = tid + 256*c;
      Wx[((size_t)row0 + r)*H2 + k] = g[k]*(outs[r][k] - mu)*rstd + bvec[k];
    }
    __syncthreads();
  }
}

// ---------------- out = hs @ dec_w^T + dec_b ----------------
__global__ __launch_bounds__(256) void decode_kernel(
    const float* __restrict__ hsbuf, const float* __restrict__ w,
    const float* __restrict__ bias, float* __restrict__ out)
{
  const int tid  = threadIdx.x;
  const int row0 = blockIdx.x * 4;
  __shared__ float hsr[4][HH];
  for (int idx = tid; idx < 4*HH; idx += 256)
    hsr[idx >> 9][idx & (HH-1)] = hsbuf[(size_t)row0*HH + idx];
  __syncthreads();
  float a0[4] = {0,0,0,0}, a1[4] = {0,0,0,0};
  const float* w0 = w + (size_t)tid*HH;
  const float* w1 = w + (size_t)(tid + 256)*HH;
  for (int j = 0; j < HH; ++j) {
    const float wv0 = w0[j], wv1 = w1[j];
    const float h0v = hsr[0][j], h1v = hsr[1][j], h2v = hsr[2][j], h3v = hsr[3][j];
    a0[0] += wv0*h0v; a0[1] += wv0*h1v; a0[2] += wv0*h2v; a0[3] += wv0*h3v;
    a1[0] += wv1*h0v; a1[1] += wv1*h1v; a1[2] += wv1*h2v; a1[3] += wv1*h3v;
  }
  const float b0 = bias[tid], b1 = bias[tid + 256];
#pragma unroll
  for (int r = 0; r < 4; ++r) {
    out[((size_t)row0 + r)*OO + tid]       = a0[r] + b0;
    out[((size_t)row0 + r)*OO + tid + 256] = a1[r] + b1;
  }
}

extern "C" void kernel_launch(void* const* d_in, const int* in_sizes, int n_in,
                              void* d_out, int out_size, void* d_ws, size_t ws_size,
                              hipStream_t stream) {
  (void)in_sizes; (void)n_in; (void)out_size; (void)ws_size;
  const float* x        = (const float*)d_in[0];
  const float* h0       = (const float*)d_in[1];
  const float* v0       = (const float*)d_in[2];
  const float* dU0      = (const float*)d_in[3];
  const float* te0      = (const float*)d_in[4];   // trace_e0
  const float* tE0      = (const float*)d_in[5];   // trace_E0
  const float* x2h_w    = (const float*)d_in[6];
  const float* x2h_b    = (const float*)d_in[7];
  const float* h2h_w    = (const float*)d_in[8];
  const float* h2h_b    = (const float*)d_in[9];
  const float* lnx_g    = (const float*)d_in[10];
  const float* lnx_b    = (const float*)d_in[11];
  const float* lnh_g    = (const float*)d_in[12];
  const float* lnh_b    = (const float*)d_in[13];
  const float* h2mod_w  = (const float*)d_in[14];
  const float* h2mod_b  = (const float*)d_in[15];
  const float* mod2h_w  = (const float*)d_in[16];
  const float* mod2h_b  = (const float*)d_in[17];
  const float* alpha    = (const float*)d_in[18];
  const float* tau_U    = (const float*)d_in[19];
  const float* dec_w    = (const float*)d_in[20];
  const float* dec_b    = (const float*)d_in[21];

  float* ws = (float*)d_ws;
  unsigned* barctl = (unsigned*)(ws + OFF_BAR);

  // 1) precompute Wx (also zeroes barrier flags/gens + LN stats each call)
  wx_ln_kernel<<<64, 256, 0, stream>>>(x, x2h_w, x2h_b, lnx_g, lnx_b,
                                       ws + OFF_WX, barctl, ws + OFF_STATS);

  // 2) persistent recurrent kernel: 256 blocks (= #CUs), 512 threads
  sgru_persistent<<<256, 512, 0, stream>>>(h0, v0, dU0, tE0, te0,
                                           h2h_w, h2h_b, lnh_g, lnh_b,
                                           h2mod_w, h2mod_b, mod2h_w, mod2h_b,
                                           alpha, tau_U, ws);

  // 3) decode
  decode_kernel<<<64, 256, 0, stream>>>(ws + OFF_HS, dec_w, dec_b, (float*)d_out);
}

// Round 3
// 194.322 us; speedup vs baseline: 25.7435x; 1.9913x over previous
//
#include <hip/hip_runtime.h>

// Problem dims
#define TT 32
#define BB 8
#define DD 512
#define HH 512
#define RR 32
#define OO 512
#define H2 1024

// d_ws float-index offsets (~1.64 MB used)
#define OFF_WX    0        // [TT*BB][H2]   262144  (pre-LN then LN'd in place)
#define OFF_HS    262144   // [TT*BB][HH]   131072
#define OFF_COLV  393216   // [2][BB][H2]    16384  (coherent Wh exchange)
#define OFF_FLAGS 409600   // 256 u32 barrier flags

#define AGENT __HIP_MEMORY_SCOPE_AGENT
#define RLX   __ATOMIC_RELAXED

__device__ __forceinline__ void st_coh(float* p, float v) {
  __hip_atomic_store(p, v, RLX, AGENT);
}
__device__ __forceinline__ float ld_coh(const float* p) {
  return __hip_atomic_load(const_cast<float*>(p), RLX, AGENT);
}
__device__ __forceinline__ float d4(const float4& a, const float4& b) {
  return a.x*b.x + a.y*b.y + a.z*b.z + a.w*b.w;
}

// ---------------- single-hop all-to-all per-batch barrier (32 blocks) ----------------
// Each block posts flag=seq (after draining its stores), then every block polls
// all 32 flags itself. One coherence round-trip; no master/generation hop.
__device__ __forceinline__ void bar32(unsigned* flags, int b, int ir,
                                      unsigned seq, int tid) {
  __syncthreads();   // compiler drains each wave's vmcnt before s_barrier
  asm volatile("s_waitcnt vmcnt(0)" ::: "memory");
  if (tid == 0)
    __hip_atomic_store(&flags[b*32 + ir], seq, RLX, AGENT);
  if (tid < 64) {
    for (;;) {
      unsigned v = (tid < 32) ? __hip_atomic_load(&flags[b*32 + tid], RLX, AGENT) : seq;
      if (__all(v >= seq)) break;
      __builtin_amdgcn_s_sleep(1);
    }
  }
  __syncthreads();
}

// ---------------- fused state-update + plast + Wh GEMV -> coherent post ----------------
// Row mapping: il = tid>>5 (row 0..15 of block), m = tid&31, elem j = 4*(m+32q)+c.
template<bool UPDATE>
__device__ __forceinline__ void gemv_step(
    int gi, int m,
    float4 (&dUr)[4], float4 (&tEr)[4],
    const float4 (&Wdvr)[4], const float4 (&wlo)[4],
    const float4 (&upr)[4], const float4 (&lor)[4],
    float s_b, float c1t, float c2t, float a_sp, float hbl, float hbh,
    const float* nh_s, const float* te_s,
    float* post)  // colvG + parity*BB*H2 + b*H2
{
  const float nh_i = nh_s[gi];
  const float te_i = UPDATE ? te_s[gi] : 0.0f;
  const float4* nh4 = reinterpret_cast<const float4*>(nh_s);
  const float4* te4 = reinterpret_cast<const float4*>(te_s);
  float plast = 0.0f, gdv = 0.0f, glo = 0.0f;
#pragma unroll
  for (int q = 0; q < 4; ++q) {
    const int J = m + 32*q;
    const float4 h4 = nh4[J];
    if (UPDATE) {
      const float4 t4 = te4[J];
#define SGRU_UPD(C) { \
      float o   = nh_i * t4.C - h4.C * te_i;                /* outer - outer^T    */ \
      float tEn = tEr[q].C + s_b * (o - tEr[q].C);          /* (1-s)tE + s*o      */ \
      tEr[q].C  = tEn;                                                               \
      float d   = c1t * dUr[q].C + c2t * tEn;               /* (1-tau)dU+tau*m*tE */ \
      d = fminf(d, upr[q].C); d = fmaxf(d, lor[q].C);       /* clip               */ \
      dUr[q].C  = d;                                                                 \
      plast = fmaf(d, h4.C, plast); }
      SGRU_UPD(x) SGRU_UPD(y) SGRU_UPD(z) SGRU_UPD(w)
#undef SGRU_UPD
    } else {
      plast += d4(dUr[q], h4);
    }
    gdv += d4(Wdvr[q], h4);
    glo += d4(wlo[q],  h4);
  }
#pragma unroll
  for (int off = 16; off >= 1; off >>= 1) {
    plast += __shfl_xor(plast, off);
    gdv   += __shfl_xor(gdv, off);
    glo   += __shfl_xor(glo, off);
  }
  if (m == 0) {
    st_coh(&post[gi],      glo + hbl);                    // low col gi
    st_coh(&post[HH + gi], gdv + hbh + a_sp * plast);     // high col HH+gi
  }
}

// ---------------- persistent recurrent kernel: 1 barrier/step ----------------
__global__ __launch_bounds__(512, 1) void sgru_persistent(
    const float* __restrict__ h0,     const float* __restrict__ v0,
    const float* __restrict__ dU0,    const float* __restrict__ tE0,
    const float* __restrict__ te0,
    const float* __restrict__ h2h_w,  const float* __restrict__ h2h_b,
    const float* __restrict__ lnh_g,  const float* __restrict__ lnh_b,
    const float* __restrict__ h2mod_w,const float* __restrict__ h2mod_b,
    const float* __restrict__ mod2h_w,const float* __restrict__ mod2h_b,
    const float* __restrict__ alpha_p,const float* __restrict__ tau_p,
    float* __restrict__ ws)
{
  const int tid = threadIdx.x;
  const int b   = blockIdx.x & 7;    // consecutive blockIdx -> XCD round-robin
  const int ir  = blockIdx.x >> 3;   // row-group 0..31
  const int i0  = ir << 4;
  const int il  = tid >> 5;
  const int m   = tid & 31;
  const int gi  = i0 + il;

  const float* Wx = ws + OFF_WX;
  float* hsbuf    = ws + OFF_HS;
  float* colvG    = ws + OFF_COLV;
  unsigned* flags = (unsigned*)(ws + OFF_FLAGS);

  __shared__ float nh_s[2][HH];        // nh double buffer by parity
  __shared__ float te_s[HH];           // block-local te (redundant)
  __shared__ float hmw_s[RR * 516];    // staged h2mod_w, padded pitch
  __shared__ float mp_s[RR];
  __shared__ float rsm_s[4];
  __shared__ float red_s[2][8];

  const float a_sp  = log1pf(__expf(alpha_p[0]));
  const float inv_a = 1.0f / (a_sp + 1e-8f);
  const float tau   = 1.0f / (1.0f + __expf(-tau_p[0]));
  const float c1t   = 1.0f - tau;

  // ---- register-resident state: dU, tE, w_dv row, w_low row, clip bounds ----
  float4 dUr[4], tEr[4], Wdvr[4], wlo[4], upr[4], lor[4];
  {
    const size_t rowoff = ((size_t)b * HH + gi) * HH;
    const size_t whioff = (size_t)(HH + gi) * HH;
    const size_t wlooff = (size_t)gi * HH;
#pragma unroll
    for (int q = 0; q < 4; ++q) {
      const int J = m + 32*q;
      dUr[q] = *reinterpret_cast<const float4*>(dU0 + rowoff + 4*J);
      tEr[q] = *reinterpret_cast<const float4*>(tE0 + rowoff + 4*J);
      wlo[q] = *reinterpret_cast<const float4*>(h2h_w + wlooff + 4*J);
      const float4 w = *reinterpret_cast<const float4*>(h2h_w + whioff + 4*J);
      Wdvr[q] = w;
      float4 u, l;
      u.x =  fmaxf(1.0f - w.x, 0.0f) * inv_a;  l.x = -fmaxf(1.0f + w.x, 0.0f) * inv_a;
      u.y =  fmaxf(1.0f - w.y, 0.0f) * inv_a;  l.y = -fmaxf(1.0f + w.y, 0.0f) * inv_a;
      u.z =  fmaxf(1.0f - w.z, 0.0f) * inv_a;  l.z = -fmaxf(1.0f + w.z, 0.0f) * inv_a;
      u.w =  fmaxf(1.0f - w.w, 0.0f) * inv_a;  l.w = -fmaxf(1.0f + w.w, 0.0f) * inv_a;
      upr[q] = u; lor[q] = l;
    }
  }

  // ---- per-thread constants in registers ----
  const float rgz = lnh_g[tid],      rbz = lnh_b[tid];
  const float rgd = lnh_g[HH + tid], rbd = lnh_b[HH + tid];
  const float hbl = h2h_b[gi], hbh = h2h_b[HH + gi];
  const float hmb = h2mod_b[tid >> 4];
  const float mw0 = (tid < RR) ? mod2h_w[tid]        : 0.0f;
  const float mw1 = (tid < RR) ? mod2h_w[RR + tid]   : 0.0f;
  const float mw2 = (tid < RR) ? mod2h_w[2*RR + tid] : 0.0f;
  const float mb0 = mod2h_b[0], mb1 = mod2h_b[1], mb2 = mod2h_b[2];
  float vreg = v0[b*HH + tid];

  // ---- prologue: stage LDS, compute Wh(0) from h0, post to buf 0 ----
  nh_s[1][tid] = h0[b*HH + tid];     // "prev" for t=0
  te_s[tid]    = te0[b*HH + tid];
  for (int idx = tid; idx < RR*HH; idx += 512)
    hmw_s[(idx >> 9)*516 + (idx & 511)] = h2mod_w[idx];
  __syncthreads();

  gemv_step<false>(gi, m, dUr, tEr, Wdvr, wlo, upr, lor,
                   0.0f, c1t, 0.0f, a_sp, hbl, hbh,
                   nh_s[1], te_s, colvG + 0*BB*H2 + b*H2);

  float wxz = Wx[(size_t)(0*BB + b)*H2 + tid];
  float wxd = Wx[(size_t)(0*BB + b)*H2 + HH + tid];

  unsigned seq = 0;
  for (int t = 0; t < TT; ++t) {
    const int cur = t & 1;
    bar32(flags, b, ir, ++seq, tid);   // all posts of buf[cur] complete

    // ---- gather the 2 Wh values this thread needs ----
    const float whz = ld_coh(&colvG[cur*BB*H2 + b*H2 + tid]);
    const float whd = ld_coh(&colvG[cur*BB*H2 + b*H2 + HH + tid]);

    // ---- LN stats over 1024 (block-redundant, bitwise identical) ----
    float s1 = whz + whd, s2 = whz*whz + whd*whd;
#pragma unroll
    for (int off = 32; off >= 1; off >>= 1) {
      s1 += __shfl_xor(s1, off);
      s2 += __shfl_xor(s2, off);
    }
    if ((tid & 63) == 0) { red_s[0][tid >> 6] = s1; red_s[1][tid >> 6] = s2; }
    __syncthreads();
    s1 = 0.0f; s2 = 0.0f;
#pragma unroll
    for (int w = 0; w < 8; ++w) { s1 += red_s[0][w]; s2 += red_s[1][w]; }
    const float mu   = s1 * (1.0f / H2);
    const float var  = s2 * (1.0f / H2) - mu * mu;
    const float rstd = rsqrtf(var + 1e-5f);

    // ---- LN + gate + v + nh (thread owns element tid) ----
    const float yz = (whz - mu)*rstd*rgz + rbz + wxz;
    const float yd = (whd - mu)*rstd*rgd + rbd + wxd;
    const float z  = 1.0f / (1.0f + __expf(-yz));
    vreg = vreg + z * (yd - vreg);
    const float nh = fmaxf(vreg, 0.0f);
    nh_s[cur][tid] = nh;
    if (ir == 0) hsbuf[(size_t)(t*BB + b)*HH + tid] = nh;
    if (t == TT - 1) return;           // uniform exit; decode kernel follows

    // prefetch next step's Wx under upcoming latency
    wxz = Wx[(size_t)((t+1)*BB + b)*H2 + tid];
    wxd = Wx[(size_t)((t+1)*BB + b)*H2 + HH + tid];
    __syncthreads();                   // nh_s[cur] ready

    // ---- modulator GEMV from LDS (redundant): r = tid>>4, kk = tid&15 ----
    {
      const int r = tid >> 4, kk = tid & 15;
      float part = 0.0f;
#pragma unroll
      for (int j = 0; j < 32; ++j)
        part += hmw_s[r*516 + kk + 16*j] * nh_s[cur][kk + 16*j];
#pragma unroll
      for (int off = 8; off >= 1; off >>= 1) part += __shfl_xor(part, off);
      if (kk == 0) mp_s[r] = fmaxf(part + hmb, 0.0f);
    }
    __syncthreads();
    if (tid < 64) {                    // wave 0: r/s/m 3x32 dots
      const float mp = (tid < RR) ? mp_s[tid] : 0.0f;
      float a0 = mw0*mp, a1 = mw1*mp, a2 = mw2*mp;
#pragma unroll
      for (int off = 16; off >= 1; off >>= 1) {
        a0 += __shfl_xor(a0, off);
        a1 += __shfl_xor(a1, off);
        a2 += __shfl_xor(a2, off);
      }
      if (tid == 0) {
        rsm_s[0] = 1.0f / (1.0f + __expf(-(a0 + mb0)));
        rsm_s[1] = 1.0f / (1.0f + __expf(-(a1 + mb1)));
        rsm_s[2] = a2 + mb2;
      }
    }
    __syncthreads();
    const float r_b = rsm_s[0];
    const float s_b = rsm_s[1];
    const float c2t = tau * rsm_s[2];

    // ---- te update (redundant): te_n = (1-r)te + r*h_prev ----
    te_s[tid] += r_b * (nh_s[1 - cur][tid] - te_s[tid]);
    __syncthreads();

    // ---- state update + Wh GEMV for next step, post to buf[1-cur] ----
    gemv_step<true>(gi, m, dUr, tEr, Wdvr, wlo, upr, lor,
                    s_b, c1t, c2t, a_sp, hbl, hbh,
                    nh_s[cur], te_s, colvG + (1 - cur)*BB*H2 + b*H2);
  }
}

// ---------------- tiled fp32 GEMM: C[M][N] = A[M][K=512] . W[N][K]^T + bias ----------------
// BM=64, BN=32, BK=32, 256 threads, 4x2 micro-tile, k-transposed padded LDS.
#define GBM 64
#define GBN 32
#define GBK 32
__global__ __launch_bounds__(256) void gemm_tn(
    const float* __restrict__ A, const float* __restrict__ W,
    const float* __restrict__ bias, float* __restrict__ C,
    int M, int N)
{
  const int K = 512;
  const int nbn = N / GBN;
  const int m0 = (blockIdx.x / nbn) * GBM;
  const int n0 = (blockIdx.x % nbn) * GBN;
  const int tid = threadIdx.x;
  const int tx = tid & 15;   // n: tx*2
  const int ty = tid >> 4;   // m: ty*4
  const int lr = tid >> 3;   // 0..31 (load row)
  const int lc = tid & 7;    // 0..7  (k float4)
  __shared__ float As[GBK][68];   // [k][m], padded, 16B-aligned rows
  __shared__ float Ws[GBK][36];   // [k][n]
  float acc[4][2] = {};
  for (int kc = 0; kc < K; kc += GBK) {
    const float4 a0 = *reinterpret_cast<const float4*>(A + (size_t)(m0 + lr)*K      + kc + lc*4);
    const float4 a1 = *reinterpret_cast<const float4*>(A + (size_t)(m0 + lr + 32)*K + kc + lc*4);
    const float4 w0 = *reinterpret_cast<const float4*>(W + (size_t)(n0 + lr)*K      + kc + lc*4);
    __syncthreads();
    As[lc*4+0][lr] = a0.x; As[lc*4+1][lr] = a0.y; As[lc*4+2][lr] = a0.z; As[lc*4+3][lr] = a0.w;
    As[lc*4+0][lr+32] = a1.x; As[lc*4+1][lr+32] = a1.y; As[lc*4+2][lr+32] = a1.z; As[lc*4+3][lr+32] = a1.w;
    Ws[lc*4+0][lr] = w0.x; Ws[lc*4+1][lr] = w0.y; Ws[lc*4+2][lr] = w0.z; Ws[lc*4+3][lr] = w0.w;
    __syncthreads();
#pragma unroll
    for (int k = 0; k < GBK; ++k) {
      const float4 am = *reinterpret_cast<const float4*>(&As[k][ty*4]);
      const float2 wn = *reinterpret_cast<const float2*>(&Ws[k][tx*2]);
      acc[0][0] += am.x*wn.x; acc[0][1] += am.x*wn.y;
      acc[1][0] += am.y*wn.x; acc[1][1] += am.y*wn.y;
      acc[2][0] += am.z*wn.x; acc[2][1] += am.z*wn.y;
      acc[3][0] += am.w*wn.x; acc[3][1] += am.w*wn.y;
    }
  }
  const float bv0 = bias[n0 + tx*2], bv1 = bias[n0 + tx*2 + 1];
#pragma unroll
  for (int i = 0; i < 4; ++i) {
    C[(size_t)(m0 + ty*4 + i)*N + n0 + tx*2]     = acc[i][0] + bv0;
    C[(size_t)(m0 + ty*4 + i)*N + n0 + tx*2 + 1] = acc[i][1] + bv1;
  }
}

// ---------------- in-place row LayerNorm over H2 columns (256 rows) ----------------
__global__ __launch_bounds__(256) void ln_apply(
    float* __restrict__ Wp, const float* __restrict__ g, const float* __restrict__ b)
{
  const int row = blockIdx.x;
  const int tid = threadIdx.x;
  float* rp = Wp + (size_t)row * H2;
  float4 v = *reinterpret_cast<const float4*>(rp + tid*4);
  float s1 = v.x + v.y + v.z + v.w;
  float s2 = v.x*v.x + v.y*v.y + v.z*v.z + v.w*v.w;
#pragma unroll
  for (int off = 32; off >= 1; off >>= 1) {
    s1 += __shfl_xor(s1, off);
    s2 += __shfl_xor(s2, off);
  }
  __shared__ float red[2][4];
  if ((tid & 63) == 0) { red[0][tid >> 6] = s1; red[1][tid >> 6] = s2; }
  __syncthreads();
  s1 = red[0][0] + red[0][1] + red[0][2] + red[0][3];
  s2 = red[1][0] + red[1][1] + red[1][2] + red[1][3];
  const float mu   = s1 * (1.0f / H2);
  const float var  = s2 * (1.0f / H2) - mu * mu;
  const float rstd = rsqrtf(var + 1e-5f);
  const float4 gv = *reinterpret_cast<const float4*>(g + tid*4);
  const float4 bv = *reinterpret_cast<const float4*>(b + tid*4);
  v.x = gv.x*(v.x - mu)*rstd + bv.x;
  v.y = gv.y*(v.y - mu)*rstd + bv.y;
  v.z = gv.z*(v.z - mu)*rstd + bv.z;
  v.w = gv.w*(v.w - mu)*rstd + bv.w;
  *reinterpret_cast<float4*>(rp + tid*4) = v;
}

extern "C" void kernel_launch(void* const* d_in, const int* in_sizes, int n_in,
                              void* d_out, int out_size, void* d_ws, size_t ws_size,
                              hipStream_t stream) {
  (void)in_sizes; (void)n_in; (void)out_size; (void)ws_size;
  const float* x        = (const float*)d_in[0];
  const float* h0       = (const float*)d_in[1];
  const float* v0       = (const float*)d_in[2];
  const float* dU0      = (const float*)d_in[3];
  const float* te0      = (const float*)d_in[4];   // trace_e0
  const float* tE0      = (const float*)d_in[5];   // trace_E0
  const float* x2h_w    = (const float*)d_in[6];
  const float* x2h_b    = (const float*)d_in[7];
  const float* h2h_w    = (const float*)d_in[8];
  const float* h2h_b    = (const float*)d_in[9];
  const float* lnx_g    = (const float*)d_in[10];
  const float* lnx_b    = (const float*)d_in[11];
  const float* lnh_g    = (const float*)d_in[12];
  const float* lnh_b    = (const float*)d_in[13];
  const float* h2mod_w  = (const float*)d_in[14];
  const float* h2mod_b  = (const float*)d_in[15];
  const float* mod2h_w  = (const float*)d_in[16];
  const float* mod2h_b  = (const float*)d_in[17];
  const float* alpha    = (const float*)d_in[18];
  const float* tau_U    = (const float*)d_in[19];
  const float* dec_w    = (const float*)d_in[20];
  const float* dec_b    = (const float*)d_in[21];

  float* ws = (float*)d_ws;
  unsigned* flags = (unsigned*)(ws + OFF_FLAGS);

  // 0) zero barrier flags (graph-capturable async memset)
  hipMemsetAsync(flags, 0, 256 * sizeof(unsigned), stream);

  // 1) Wx pre-LN GEMM: [256 x 1024] = x[256 x 512] . x2h_w^T  (128 blocks)
  gemm_tn<<<(TT*BB/GBM) * (H2/GBN), 256, 0, stream>>>(x, x2h_w, x2h_b,
                                                      ws + OFF_WX, TT*BB, H2);
  // 2) LN in place (256 rows)
  ln_apply<<<TT*BB, 256, 0, stream>>>(ws + OFF_WX, lnx_g, lnx_b);

  // 3) persistent recurrent kernel: 256 blocks (= #CUs), 512 threads
  sgru_persistent<<<256, 512, 0, stream>>>(h0, v0, dU0, tE0, te0,
                                           h2h_w, h2h_b, lnh_g, lnh_b,
                                           h2mod_w, h2mod_b, mod2h_w, mod2h_b,
                                           alpha, tau_U, ws);

  // 4) decode GEMM: out[256 x 512] = hs . dec_w^T + dec_b  (64 blocks)
  gemm_tn<<<(TT*BB/GBM) * (OO/GBN), 256, 0, stream>>>(ws + OFF_HS, dec_w, dec_b,
                                                      (float*)d_out, TT*BB, OO);
}